// Round 2
// 1863.789 us; speedup vs baseline: 1.1768x; 1.1768x over previous
//
#include <hip/hip_runtime.h>
#include <stdint.h>

// Problem constants
#define BDIM 8192
#define PDIM 4096
#define DDIM 1024
#define LDIM 5
#define KSEL 5
#define EPSV 1e-8f

// bf16-split GEMM config
#define KSPL 2048            // per-row bf16 storage: [hi(1024) | lo(1024)]
#define KPROD 3072           // augmented K: hi*hi + lo*hi + hi*lo
#define GBK 32               // K-step (one mfma_16x16x32)
#define NCB (PDIM / 128)     // 32 col-blocks
#define NCAND (NCB * 8)      // 256 screened candidates per row

typedef unsigned long long u64;
typedef __bf16 bf16x8 __attribute__((ext_vector_type(8)));
typedef float f32x4 __attribute__((ext_vector_type(4)));

struct __align__(8) bf4 { __bf16 h[4]; };

// Packed candidate: (float_bits(dist) << 32) | key_index. dist > 0 always here,
// so unsigned u64 compare == lexicographic (dist asc, idx asc) == lax.top_k order.
__device__ __forceinline__ void insert5(u64 t[5], u64 c) {
    if (c < t[4]) {
        if (c < t[3]) { t[4] = t[3];
            if (c < t[2]) { t[3] = t[2];
                if (c < t[1]) { t[2] = t[1];
                    if (c < t[0]) { t[1] = t[0]; t[0] = c; }
                    else t[1] = c;
                } else t[2] = c;
            } else t[3] = c;
        } else t[4] = c;
    }
}

__device__ __forceinline__ void insert8(u64 t[8], u64 c) {
    if (c < t[7]) {                 // rare-taken: one compare in the common case
        t[7] = c;
        #pragma unroll
        for (int i = 7; i > 0; --i) {   // one bubble pass restores sortedness
            u64 a = t[i - 1], b = t[i];
            u64 lo = b < a ? b : a;
            u64 hi = b < a ? a : b;
            t[i - 1] = lo; t[i] = hi;
        }
    }
}

// async global->LDS, 16B per lane, linear dest (wave base + lane*16)
__device__ __forceinline__ void gload16(const void* g, void* l) {
    __builtin_amdgcn_global_load_lds(
        (const __attribute__((address_space(1))) uint32_t*)g,
        (__attribute__((address_space(3))) uint32_t*)(uintptr_t)l,
        16, 0, 0);
}

// Kernel 1: split fp32 rows into (hi, lo) bf16 halves + exact fp32 row norms.
// Blocks 0..P-1 -> keys, P..P+B-1 -> x. hi = rne(v), lo = rne(v - hi):
// residual ~2^-18 relative -> cos error ~1e-7, far below top-k gaps (~2e-3).
__global__ __launch_bounds__(256) void convert_split_kernel(
        const float* __restrict__ x, const float* __restrict__ keys,
        __bf16* __restrict__ Xc, __bf16* __restrict__ Kc,
        float* __restrict__ xn, float* __restrict__ kn) {
    int b = blockIdx.x;
    const float* src; __bf16* dst; float* nrm;
    if (b < PDIM) { src = keys + (size_t)b * DDIM; dst = Kc + (size_t)b * KSPL; nrm = kn + b; }
    else { int r = b - PDIM; src = x + (size_t)r * DDIM; dst = Xc + (size_t)r * KSPL; nrm = xn + r; }
    float4 v = ((const float4*)src)[threadIdx.x];     // 256 * 4 = 1024
    float f[4] = {v.x, v.y, v.z, v.w};
    bf4 hi, lo;
    #pragma unroll
    for (int i = 0; i < 4; ++i) {
        __bf16 h = (__bf16)f[i];
        hi.h[i] = h;
        lo.h[i] = (__bf16)(f[i] - (float)h);
    }
    *(bf4*)(dst + (size_t)threadIdx.x * 4) = hi;
    *(bf4*)(dst + 1024 + (size_t)threadIdx.x * 4) = lo;
    float s = v.x * v.x + v.y * v.y + v.z * v.z + v.w * v.w;
    #pragma unroll
    for (int m = 32; m; m >>= 1) s += __shfl_xor(s, m, 64);
    __shared__ float red[4];
    if ((threadIdx.x & 63) == 0) red[threadIdx.x >> 6] = s;
    __syncthreads();
    if (threadIdx.x == 0) *nrm = sqrtf(red[0] + red[1] + red[2] + red[3]);
}

// Kernel 2: 128x128-tile bf16 MFMA GEMM over K'=3072 (m97 structure:
// single-buffered LDS, global_load_lds width 16, 2 barriers per K-step),
// fused epilogue: dist -> per-row top-8 within this 128-col block -> part[].
// K'-segments: A = [hi|lo|hi] -> asrc = kc % 2048; B = [hi|hi|lo] -> bsrc = kc<1024 ? kc : kc-1024.
__global__ __launch_bounds__(256, 2) void gemm_topk_kernel(
        const __bf16* __restrict__ Xc, const __bf16* __restrict__ Kc,
        const float* __restrict__ xn, const float* __restrict__ kn,
        u64* __restrict__ part) {
    __shared__ union {
        struct { __bf16 A[128 * GBK]; __bf16 B[128 * GBK]; } g;   // 8KB + 8KB
        float slab[64 * 128];                                      // 32KB (epilogue)
    } sm;

    const int tid = threadIdx.x;
    const int lane = tid & 63;
    const int w = tid >> 6, wr = w >> 1, wc = w & 1;   // 4 waves, 2x2 of 64x64
    const int row0 = blockIdx.y * 128;
    const int col0 = blockIdx.x * 128;
    const int fr = lane & 15, fq = lane >> 4;

    f32x4 acc[4][4];
    #pragma unroll
    for (int m = 0; m < 4; ++m)
        #pragma unroll
        for (int n = 0; n < 4; ++n)
            #pragma unroll
            for (int r = 0; r < 4; ++r) acc[m][n][r] = 0.f;

    for (int kc = 0; kc < KPROD; kc += GBK) {
        const int asrc = (kc < 2048) ? kc : kc - 2048;
        const int bsrc = (kc < 1024) ? kc : kc - 1024;
        __syncthreads();               // previous step's ds_reads done
        #pragma unroll
        for (int i = 0; i < 2; ++i) {  // 128x32 bf16 = 512 chunks of 16B, 2 rounds
            int chunk = i * 256 + tid;
            int r = chunk >> 2, k8 = (chunk & 3) << 3;
            gload16(Xc + (size_t)(row0 + r) * KSPL + asrc + k8, sm.g.A + chunk * 8);
            gload16(Kc + (size_t)(col0 + r) * KSPL + bsrc + k8, sm.g.B + chunk * 8);
        }
        __syncthreads();               // compiler drains vmcnt before s_barrier
        bf16x8 af[4], bb[4];
        #pragma unroll
        for (int m = 0; m < 4; ++m)
            af[m] = *(const bf16x8*)&sm.g.A[(wr * 64 + m * 16 + fr) * GBK + fq * 8];
        #pragma unroll
        for (int n = 0; n < 4; ++n)
            bb[n] = *(const bf16x8*)&sm.g.B[(wc * 64 + n * 16 + fr) * GBK + fq * 8];
        #pragma unroll
        for (int m = 0; m < 4; ++m)
            #pragma unroll
            for (int n = 0; n < 4; ++n)
                acc[m][n] = __builtin_amdgcn_mfma_f32_16x16x32_bf16(af[m], bb[n], acc[m][n], 0, 0, 0);
    }

    // norms for this wave's rows/cols (L1/L2-resident)
    float knv[4], xnv[4][4];
    #pragma unroll
    for (int n = 0; n < 4; ++n) knv[n] = kn[col0 + wc * 64 + n * 16 + fr];
    #pragma unroll
    for (int m = 0; m < 4; ++m)
        #pragma unroll
        for (int r = 0; r < 4; ++r)
            xnv[m][r] = xn[row0 + wr * 64 + m * 16 + fq * 4 + r];

    // Epilogue in two halves of 64 rows: regs -> dist slab -> per-row top-8.
    // C/D layout (verified m89/m91): col = lane&15, row = (lane>>4)*4 + reg.
    #pragma unroll
    for (int mh = 0; mh < 2; ++mh) {
        __syncthreads();
        #pragma unroll
        for (int ml = 0; ml < 2; ++ml) {
            int m = mh * 2 + ml;
            #pragma unroll
            for (int n = 0; n < 4; ++n) {
                #pragma unroll
                for (int r = 0; r < 4; ++r) {
                    float denom = fmaxf(xnv[m][r] * knv[n], EPSV);
                    float dist = 1.0f - acc[m][n][r] / denom;
                    int sr = wr * 32 + ml * 16 + fq * 4 + r;
                    int sc = wc * 64 + n * 16 + fr;
                    sm.slab[sr * 128 + sc] = dist;   // screening only; refined later
                }
            }
        }
        __syncthreads();
        const int sr = tid >> 2, seg = tid & 3;     // 4 threads per slab row
        const int grow = row0 + (sr >> 5) * 64 + mh * 32 + (sr & 31);
        u64 t8[8];
        #pragma unroll
        for (int k = 0; k < 8; ++k) t8[k] = ~0ULL;
        #pragma unroll
        for (int j = 0; j < 32; ++j) {
            int c = seg * 32 + ((j + sr + seg * 8) & 31);   // rotate to spread banks
            float d = sm.slab[sr * 128 + c];
            insert8(t8, ((u64)__float_as_uint(d) << 32) | (unsigned)(col0 + c));
        }
        #pragma unroll
        for (int mm = 1; mm <= 2; mm <<= 1) {       // merge the 4 same-row threads
            u64 o[8];
            #pragma unroll
            for (int k = 0; k < 8; ++k) o[k] = __shfl_xor(t8[k], mm, 64);
            #pragma unroll
            for (int k = 0; k < 8; ++k) insert8(t8, o[k]);
        }
        if (seg == 0) {
            u64* p = part + ((size_t)grow * NCB + blockIdx.x) * 8;
            #pragma unroll
            for (int k = 0; k < 8; ++k) p[k] = t8[k];
        }
    }
}

// Kernel 3: per row: merge 256 screened candidates -> approx top-8 ->
// exact fp32 recompute of those 8 -> final top-5 indices + row loss.
// Consumes part (which lives in the out buffer); writes only small ws arrays,
// so the out buffer is dead as scratch after this kernel completes.
__global__ __launch_bounds__(256) void select_kernel(
        const u64* __restrict__ part,
        const float* __restrict__ x, const float* __restrict__ keys,
        const float* __restrict__ xn, const float* __restrict__ kn,
        int* __restrict__ sidx, float* __restrict__ row_loss) {
    const int row = blockIdx.x;
    const int tid = threadIdx.x;
    __shared__ u64 cand8[8];
    __shared__ u64 ex8[8];

    if (tid < 64) {                       // wave 0: merge 256 -> approx top-8
        u64 t8[8];
        #pragma unroll
        for (int k = 0; k < 8; ++k) t8[k] = ~0ULL;
        const u64* p = part + (size_t)row * NCAND;
        #pragma unroll
        for (int i = 0; i < 4; ++i) insert8(t8, p[tid + i * 64]);
        #pragma unroll
        for (int mm = 1; mm <= 32; mm <<= 1) {
            u64 o[8];
            #pragma unroll
            for (int k = 0; k < 8; ++k) o[k] = __shfl_xor(t8[k], mm, 64);
            #pragma unroll
            for (int k = 0; k < 8; ++k) insert8(t8, o[k]);
        }
        if (tid == 0) {
            #pragma unroll
            for (int k = 0; k < 8; ++k) cand8[k] = t8[k];
        }
    }
    __syncthreads();

    // exact fp32 dot for the 8 candidates: wave w handles candidates 2w, 2w+1
    const int w = tid >> 6, lane = tid & 63;
    const float* xr = x + (size_t)row * DDIM;
    #pragma unroll
    for (int ci = 0; ci < 2; ++ci) {
        int cidx = (int)(cand8[w * 2 + ci] & 0xFFFFFFFFULL);
        const float* kr = keys + (size_t)cidx * DDIM;
        float s = 0.f;
        #pragma unroll
        for (int j = 0; j < DDIM / 64; ++j)
            s += xr[j * 64 + lane] * kr[j * 64 + lane];
        #pragma unroll
        for (int mm = 32; mm; mm >>= 1) s += __shfl_xor(s, mm, 64);
        if (lane == 0) {
            float denom = fmaxf(xn[row] * kn[cidx], EPSV);
            float dist = 1.0f - s / denom;
            ex8[w * 2 + ci] = ((u64)__float_as_uint(dist) << 32) | (unsigned)cidx;
        }
    }
    __syncthreads();
    if (tid == 0) {
        u64 t[5] = {~0ULL, ~0ULL, ~0ULL, ~0ULL, ~0ULL};
        #pragma unroll
        for (int i = 0; i < 8; ++i) insert5(t, ex8[i]);
        float ls = 0.f;
        #pragma unroll
        for (int k = 0; k < KSEL; ++k) {
            sidx[row * KSEL + k] = (int)(t[k] & 0xFFFFFFFFULL);
            ls += __uint_as_float((unsigned)(t[k] >> 32));
        }
        row_loss[row] = ls;
    }
}

// Kernel 4: gather value rows into out (overwrites every prompt byte,
// including the regions used as scratch by kernels 1-3).
__global__ __launch_bounds__(256) void gather_kernel(
        const int* __restrict__ sidx, const float* __restrict__ values,
        float* __restrict__ out) {
    const int row = blockIdx.x;
    const int tid = threadIdx.x;
    float4* dst = (float4*)(out + (size_t)row * (KSEL * LDIM * DDIM));
    #pragma unroll
    for (int k = 0; k < KSEL; ++k) {
        const float4* src = (const float4*)(values + (size_t)sidx[row * KSEL + k] * (LDIM * DDIM));
        float4* dstk = dst + k * (LDIM * DDIM / 4);
        for (int o = tid; o < LDIM * DDIM / 4; o += 256) dstk[o] = src[o];
    }
}

// Kernel 5: deterministic loss reduction
__global__ __launch_bounds__(256) void loss_reduce_kernel(
        const float* __restrict__ row_loss, float* __restrict__ out_loss) {
    float s = 0.f;
    for (int i = threadIdx.x; i < BDIM; i += 256) s += row_loss[i];
    #pragma unroll
    for (int m = 32; m; m >>= 1) s += __shfl_xor(s, m, 64);
    __shared__ float red[4];
    if ((threadIdx.x & 63) == 0) red[threadIdx.x >> 6] = s;
    __syncthreads();
    if (threadIdx.x == 0)
        *out_loss = (red[0] + red[1] + red[2] + red[3]) * (1.0f / (BDIM * KSEL));
}

extern "C" void kernel_launch(void* const* d_in, const int* in_sizes, int n_in,
                              void* d_out, int out_size, void* d_ws, size_t ws_size,
                              hipStream_t stream) {
    const float* x      = (const float*)d_in[0];   // (B,1,D)
    const float* keys   = (const float*)d_in[1];   // (P,D)
    const float* values = (const float*)d_in[2];   // (P,L,D)
    float* out = (float*)d_out;                    // prompts (B*K*L*D floats) then loss (1)

    // Big scratch lives inside the 800 MB out buffer (dead before gather
    // overwrites it; stream order serializes). Small arrays (~240 KB) in ws —
    // the previous session verified ~2.7 MB of ws works.
    char* big = (char*)d_out;
    __bf16* Xc  = (__bf16*)big;                    // 8192*2048*2 = 33,554,432 B
    __bf16* Kc  = (__bf16*)(big + 33554432);       // 4096*2048*2 = 16,777,216 B
    u64*   part = (u64*)  (big + 50331648);        // 8192*256*8  = 16,777,216 B (total 67.1 MB << 800 MB)

    char* ws = (char*)d_ws;
    float* xn       = (float*)ws;                  // 32,768 B
    float* kn       = (float*)(ws + 32768);        // 16,384 B
    float* row_loss = (float*)(ws + 49152);        // 32,768 B
    int*   sidx     = (int*)  (ws + 81920);        // 163,840 B  (total 240 KB)

    convert_split_kernel<<<PDIM + BDIM, 256, 0, stream>>>(x, keys, Xc, Kc, xn, kn);
    gemm_topk_kernel<<<dim3(NCB, BDIM / 128), 256, 0, stream>>>(Xc, Kc, xn, kn, part);
    select_kernel<<<BDIM, 256, 0, stream>>>(part, x, keys, xn, kn, sidx, row_loss);
    gather_kernel<<<BDIM, 256, 0, stream>>>(sidx, values, out);
    loss_reduce_kernel<<<1, 256, 0, stream>>>(row_loss, out + (size_t)BDIM * KSEL * LDIM * DDIM);
}